// Round 6
// baseline (467.895 us; speedup 1.0000x reference)
//
#include <hip/hip_runtime.h>
#include <stdint.h>

#define NRAYS   262144
#define NSAMP   256
#define RPB     16
#define TFINALF 1e10f
#define EPSF    1e-5f
#define CSTR    68     // cdf row stride (floats)
#define SSTR2   164    // half-staging row stride (floats)
#define SKEW    20     // sub-row skew (floats), 16B aligned

template<int CTRL>
__device__ __forceinline__ uint32_t dppi(uint32_t x) {
    return (uint32_t)__builtin_amdgcn_update_dpp(0, (int)x, CTRL, 0xF, 0xF, false);
}
template<int CTRL>
__device__ __forceinline__ float dppf(float x) {
    return __int_as_float(__builtin_amdgcn_update_dpp(0, __float_as_int(x), CTRL, 0xF, 0xF, false));
}

// inclusive +scan across each 16-lane row
__device__ __forceinline__ float row16_iscan(float x) {
    x += dppf<0x111>(x);
    x += dppf<0x112>(x);
    x += dppf<0x114>(x);
    x += dppf<0x118>(x);
    return x;
}

__device__ __forceinline__ void celo(uint32_t& a, uint32_t& b) {
    uint32_t mn = min(a, b), mx = max(a, b);
    a = mn; b = mx;
}

// cross-lane FLIP pass: partner = mirror-lane (CTRL), element 15-j; up lanes keep max
template<int CTRL>
__device__ __forceinline__ void flipx(uint32_t w[16], bool up) {
#pragma unroll
    for (int p = 0; p < 8; ++p) {
        uint32_t a = w[p], b = w[15 - p];
        uint32_t oa = dppi<CTRL>(b);   // partner lane's w[15-p]
        uint32_t ob = dppi<CTRL>(a);   // partner lane's w[p]
        w[p]      = up ? max(a, oa) : min(a, oa);
        w[15 - p] = up ? max(b, ob) : min(b, ob);
    }
}

// cross-lane XOR pass, same element index; up lanes keep max
template<int CTRL>
__device__ __forceinline__ void jsx(uint32_t w[16], bool up) {
#pragma unroll
    for (int j = 0; j < 16; ++j) {
        uint32_t o = dppi<CTRL>(w[j]);
        w[j] = up ? max(w[j], o) : min(w[j], o);
    }
}
// lane^4 via ds_swizzle (offload to DS pipe)
__device__ __forceinline__ void jsx_swz4(uint32_t w[16], bool up) {
#pragma unroll
    for (int j = 0; j < 16; ++j) {
        uint32_t o = (uint32_t)__builtin_amdgcn_ds_swizzle((int)w[j], 0x101F);
        w[j] = up ? max(w[j], o) : min(w[j], o);
    }
}

// in-lane min-low passes (static)
__device__ __forceinline__ void il_js8(uint32_t w[16]) {
#pragma unroll
    for (int j = 0; j < 8; ++j) celo(w[j], w[j + 8]);
}
__device__ __forceinline__ void il_js4(uint32_t w[16]) {
#pragma unroll
    for (int h = 0; h < 16; h += 8)
#pragma unroll
        for (int j = 0; j < 4; ++j) celo(w[h + j], w[h + j + 4]);
}
__device__ __forceinline__ void il_js2(uint32_t w[16]) {
#pragma unroll
    for (int h = 0; h < 16; h += 4) { celo(w[h], w[h + 2]); celo(w[h + 1], w[h + 3]); }
}
__device__ __forceinline__ void il_js1(uint32_t w[16]) {
#pragma unroll
    for (int j = 0; j < 16; j += 2) celo(w[j], w[j + 1]);
}

// normalized bitonic sort of 256 (16 lanes x 16 elems, e = lp*16 + j), ascending
__device__ __forceinline__ void sort256(uint32_t w[16], int lane) {
    // m=2
    il_js1(w);
    // m=4: flip + js1
#pragma unroll
    for (int h = 0; h < 16; h += 4) { celo(w[h], w[h + 3]); celo(w[h + 1], w[h + 2]); }
    il_js1(w);
    // m=8
#pragma unroll
    for (int h = 0; h < 16; h += 8) {
        celo(w[h], w[h + 7]); celo(w[h + 1], w[h + 6]);
        celo(w[h + 2], w[h + 5]); celo(w[h + 3], w[h + 4]);
    }
    il_js2(w); il_js1(w);
    // m=16
#pragma unroll
    for (int j = 0; j < 8; ++j) celo(w[j], w[15 - j]);
    il_js4(w); il_js2(w); il_js1(w);

    const bool b1 = (lane & 1) != 0, b2 = (lane & 2) != 0;
    const bool b4 = (lane & 4) != 0, b8 = (lane & 8) != 0;
    // m=32: flip across lane^1 (mirror within 2 lanes)
    flipx<0xB1>(w, b1);
    il_js8(w); il_js4(w); il_js2(w); il_js1(w);
    // m=64: flip mirror within 4 lanes (quad_perm [3,2,1,0])
    flipx<0x1B>(w, b2);
    jsx<0xB1>(w, b1);
    il_js8(w); il_js4(w); il_js2(w); il_js1(w);
    // m=128: flip row_half_mirror
    flipx<0x141>(w, b4);
    jsx<0x4E>(w, b2);
    jsx<0xB1>(w, b1);
    il_js8(w); il_js4(w); il_js2(w); il_js1(w);
    // m=256: flip row_mirror
    flipx<0x140>(w, b8);
    jsx_swz4(w, b4);
    jsx<0x4E>(w, b2);
    jsx<0xB1>(w, b1);
    il_js8(w); il_js4(w); il_js2(w); il_js1(w);
}

__global__ __launch_bounds__(256, 8) void informed_sampler_kernel(
    const float* __restrict__ tnear,
    const float* __restrict__ tfar,
    const float* __restrict__ dnorm,
    const float* __restrict__ density,
    const float* __restrict__ u,
    float* __restrict__ out)
{
    __shared__ float s_cdf[8 + RPB * CSTR];   // row c at 8 + c*68; row[i] = cdf[i+1]
    __shared__ float s2[RPB * SSTR2];         // half-staging: rank s at c*164 + (s>>4 mod 8)*20 + (s&15)

    const int tid  = threadIdx.x;
    const int lane = tid & 63;
    const int lp   = lane & 15;
    const int c    = tid >> 4;        // ray within block (0..15)
    const int r0   = blockIdx.x * RPB;
    const int r    = r0 + c;

    const float tn  = tnear[r];
    const float tff = tfar[r];
    const float dn  = dnorm[r];
    const float td  = tff - tn;
    const float inv63 = 1.0f / 63.0f;

    // ---- load u: lane lp holds elements e = lp*16 + j ----
    const float4* ub = reinterpret_cast<const float4*>(u + (size_t)r * NSAMP);
    uint32_t w[16];
    {
        float4 a0 = ub[lp * 4 + 0], a1 = ub[lp * 4 + 1], a2 = ub[lp * 4 + 2], a3 = ub[lp * 4 + 3];
        w[ 0]=__float_as_uint(a0.x); w[ 1]=__float_as_uint(a0.y); w[ 2]=__float_as_uint(a0.z); w[ 3]=__float_as_uint(a0.w);
        w[ 4]=__float_as_uint(a1.x); w[ 5]=__float_as_uint(a1.y); w[ 6]=__float_as_uint(a1.z); w[ 7]=__float_as_uint(a1.w);
        w[ 8]=__float_as_uint(a2.x); w[ 9]=__float_as_uint(a2.y); w[10]=__float_as_uint(a2.z); w[11]=__float_as_uint(a2.w);
        w[12]=__float_as_uint(a3.x); w[13]=__float_as_uint(a3.y); w[14]=__float_as_uint(a3.z); w[15]=__float_as_uint(a3.w);
    }

    // ---- CDF build: lane lp owns bins b0..b0+3 ----
    const int b0 = lp * 4;
    float de0 = density[(size_t)(b0 + 0) * NRAYS + r];
    float de1 = density[(size_t)(b0 + 1) * NRAYS + r];
    float de2 = density[(size_t)(b0 + 2) * NRAYS + r];
    float de3 = density[(size_t)(b0 + 3) * NRAYS + r];

    float dl  = td * inv63;
    float dl3 = (lp == 15) ? (TFINALF - (tn + td)) : dl;
    float sd0 = de0 * dl * dn, sd1 = de1 * dl * dn, sd2 = de2 * dl * dn, sd3 = de3 * dl3 * dn;

    float p0 = sd0, p1 = p0 + sd1, p2 = p1 + sd2, p3 = p2 + sd3;
    float tsc   = row16_iscan(p3);
    float carry = dppf<0x111>(tsc);              // exclusive lane-carry (lane0 -> 0, no cancellation)
    float x0 = carry, x1 = carry + p0, x2 = carry + p1, x3 = carry + p2, x4 = carry + p3;
    float e0 = __expf(-x0), e1 = __expf(-x1), e2 = __expf(-x2), e3 = __expf(-x3), e4 = __expf(-x4);
    float wv0 = e0 - e1 + EPSF, wv1 = e1 - e2 + EPSF, wv2 = e2 - e3 + EPSF, wv3 = e3 - e4 + EPSF;
    float q0 = wv0, q1 = q0 + wv1, q2 = q1 + wv2, q3 = q2 + wv3;
    float tww = row16_iscan(q3);
    float cw  = dppf<0x111>(tww);
    float tot = __int_as_float(__builtin_amdgcn_ds_swizzle(__float_as_int(tww), 0x1F0)); // bcast lane15 of 16-group
    float inv = __builtin_amdgcn_rcpf(tot);

    float* cdfrow = &s_cdf[8 + c * CSTR];
    *reinterpret_cast<float4*>(cdfrow + b0) =
        make_float4((cw + q0) * inv, (cw + q1) * inv, (cw + q2) * inv, (cw + q3) * inv);
    __asm__ volatile("s_waitcnt lgkmcnt(0)" ::: "memory");   // wave-local: own group's writes visible
    __builtin_amdgcn_sched_barrier(0);

    // ---- sort u (bits) ascending across the 16-lane group ----
    sort256(w, lane);

    // ---- inverse-CDF: binary search once, then monotone walk ----
    int b = 0;
    {
        float uq0 = __uint_as_float(w[0]);
#pragma unroll
        for (int s = 32; s >= 1; s >>= 1)
            if (cdfrow[b + s - 1] <= uq0) b += s;
    }
    float cb = (b == 0) ? 0.0f : cdfrow[b - 1];  // b=0 reads front pad (selected away)
    float ca = cdfrow[b];
#pragma unroll
    for (int j = 0; j < 16; ++j) {
        float uq = __uint_as_float(w[j]);
        while (ca <= uq && b < 63) { ++b; cb = ca; ca = cdfrow[b]; }
        float dnm = ca - cb;
        dnm = (dnm < EPSF) ? 1.0f : dnm;
        float fb = (float)b;
        float eb = (b == 0)  ? tn  : tn + td * ((fb - 0.5f) * inv63);
        float ea = (b == 63) ? tff : tn + td * ((fb + 0.5f) * inv63);
        float smp = eb + (uq - cb) * __builtin_amdgcn_rcpf(dnm) * (ea - eb);
        smp = fminf(fmaxf(smp, tn), tff);        // exact bounds; NaN-absorbing
        w[j] = __float_as_uint(smp);
    }

    // ---- two-phase transposed output (half-size staging -> 8 blocks/CU) ----
    float* s2row = &s2[c * SSTR2];
    const int g16 = tid >> 4;       // == c
    const int cc  = tid & 15;

    if (lp < 8) {                    // ranks 0..127
#pragma unroll
        for (int q = 0; q < 4; ++q)
            *reinterpret_cast<uint4*>(&s2row[lp * SKEW + q * 4]) =
                make_uint4(w[4 * q], w[4 * q + 1], w[4 * q + 2], w[4 * q + 3]);
    }
    __syncthreads();
#pragma unroll
    for (int it = 0; it < 8; ++it) {
        int s = it * 16 + g16;
        out[(size_t)s * NRAYS + r0 + cc] = s2[cc * SSTR2 + it * SKEW + g16];
    }
    __syncthreads();
    if (lp >= 8) {                   // ranks 128..255
#pragma unroll
        for (int q = 0; q < 4; ++q)
            *reinterpret_cast<uint4*>(&s2row[(lp - 8) * SKEW + q * 4]) =
                make_uint4(w[4 * q], w[4 * q + 1], w[4 * q + 2], w[4 * q + 3]);
    }
    __syncthreads();
#pragma unroll
    for (int it = 0; it < 8; ++it) {
        int s = 128 + it * 16 + g16;
        out[(size_t)s * NRAYS + r0 + cc] = s2[cc * SSTR2 + it * SKEW + g16];
    }
}

extern "C" void kernel_launch(void* const* d_in, const int* in_sizes, int n_in,
                              void* d_out, int out_size, void* d_ws, size_t ws_size,
                              hipStream_t stream) {
    const float* tnear   = (const float*)d_in[0];
    const float* tfar    = (const float*)d_in[1];
    const float* dnorm   = (const float*)d_in[2];
    const float* density = (const float*)d_in[3];
    const float* u       = (const float*)d_in[4];
    float* out = (float*)d_out;

    dim3 grid(NRAYS / RPB);
    dim3 block(256);
    hipLaunchKernelGGL(informed_sampler_kernel, grid, block, 0, stream,
                       tnear, tfar, dnorm, density, u, out);
}

// Round 7
// 307.626 us; speedup vs baseline: 1.5210x; 1.5210x over previous
//
#include <hip/hip_runtime.h>
#include <stdint.h>

#define NRAYS   262144
#define NSAMP   256
#define RPB     16
#define TFINALF 1e10f
#define EPSF    1e-5f
#define CSTR    68     // cdf row stride (floats)
#define SSTR2   164    // half-staging row stride (floats)
#define SKEW    20     // sub-row skew (floats), 16B aligned

template<int CTRL>
__device__ __forceinline__ uint32_t dppi(uint32_t x) {
    return (uint32_t)__builtin_amdgcn_update_dpp(0, (int)x, CTRL, 0xF, 0xF, false);
}
template<int CTRL>
__device__ __forceinline__ float dppf(float x) {
    return __int_as_float(__builtin_amdgcn_update_dpp(0, __float_as_int(x), CTRL, 0xF, 0xF, false));
}

// inclusive +scan across each 16-lane row
__device__ __forceinline__ float row16_iscan(float x) {
    x += dppf<0x111>(x);
    x += dppf<0x112>(x);
    x += dppf<0x114>(x);
    x += dppf<0x118>(x);
    return x;
}

__device__ __forceinline__ void celo(uint32_t& a, uint32_t& b) {
    uint32_t mn = min(a, b), mx = max(a, b);
    a = mn; b = mx;
}

// cross-lane FLIP pass: partner = mirror-lane (CTRL), element 15-j; up lanes keep max
template<int CTRL>
__device__ __forceinline__ void flipx(uint32_t w[16], bool up) {
#pragma unroll
    for (int p = 0; p < 8; ++p) {
        uint32_t a = w[p], b = w[15 - p];
        uint32_t oa = dppi<CTRL>(b);   // partner lane's w[15-p]
        uint32_t ob = dppi<CTRL>(a);   // partner lane's w[p]
        w[p]      = up ? max(a, oa) : min(a, oa);
        w[15 - p] = up ? max(b, ob) : min(b, ob);
    }
}

// cross-lane XOR pass, same element index; up lanes keep max
template<int CTRL>
__device__ __forceinline__ void jsx(uint32_t w[16], bool up) {
#pragma unroll
    for (int j = 0; j < 16; ++j) {
        uint32_t o = dppi<CTRL>(w[j]);
        w[j] = up ? max(w[j], o) : min(w[j], o);
    }
}
// lane^4 via ds_swizzle (offload to DS pipe)
__device__ __forceinline__ void jsx_swz4(uint32_t w[16], bool up) {
#pragma unroll
    for (int j = 0; j < 16; ++j) {
        uint32_t o = (uint32_t)__builtin_amdgcn_ds_swizzle((int)w[j], 0x101F);
        w[j] = up ? max(w[j], o) : min(w[j], o);
    }
}

// in-lane min-low passes (static)
__device__ __forceinline__ void il_js8(uint32_t w[16]) {
#pragma unroll
    for (int j = 0; j < 8; ++j) celo(w[j], w[j + 8]);
}
__device__ __forceinline__ void il_js4(uint32_t w[16]) {
#pragma unroll
    for (int h = 0; h < 16; h += 8)
#pragma unroll
        for (int j = 0; j < 4; ++j) celo(w[h + j], w[h + j + 4]);
}
__device__ __forceinline__ void il_js2(uint32_t w[16]) {
#pragma unroll
    for (int h = 0; h < 16; h += 4) { celo(w[h], w[h + 2]); celo(w[h + 1], w[h + 3]); }
}
__device__ __forceinline__ void il_js1(uint32_t w[16]) {
#pragma unroll
    for (int j = 0; j < 16; j += 2) celo(w[j], w[j + 1]);
}

// normalized bitonic sort of 256 (16 lanes x 16 elems, e = lp*16 + j), ascending
__device__ __forceinline__ void sort256(uint32_t w[16], int lane) {
    // m=2
    il_js1(w);
    // m=4: flip + js1
#pragma unroll
    for (int h = 0; h < 16; h += 4) { celo(w[h], w[h + 3]); celo(w[h + 1], w[h + 2]); }
    il_js1(w);
    // m=8
#pragma unroll
    for (int h = 0; h < 16; h += 8) {
        celo(w[h], w[h + 7]); celo(w[h + 1], w[h + 6]);
        celo(w[h + 2], w[h + 5]); celo(w[h + 3], w[h + 4]);
    }
    il_js2(w); il_js1(w);
    // m=16
#pragma unroll
    for (int j = 0; j < 8; ++j) celo(w[j], w[15 - j]);
    il_js4(w); il_js2(w); il_js1(w);

    const bool b1 = (lane & 1) != 0, b2 = (lane & 2) != 0;
    const bool b4 = (lane & 4) != 0, b8 = (lane & 8) != 0;
    // m=32: flip across lane^1 (mirror within 2 lanes)
    flipx<0xB1>(w, b1);
    il_js8(w); il_js4(w); il_js2(w); il_js1(w);
    // m=64: flip mirror within 4 lanes (quad_perm [3,2,1,0])
    flipx<0x1B>(w, b2);
    jsx<0xB1>(w, b1);
    il_js8(w); il_js4(w); il_js2(w); il_js1(w);
    // m=128: flip row_half_mirror
    flipx<0x141>(w, b4);
    jsx<0x4E>(w, b2);
    jsx<0xB1>(w, b1);
    il_js8(w); il_js4(w); il_js2(w); il_js1(w);
    // m=256: flip row_mirror
    flipx<0x140>(w, b8);
    jsx_swz4(w, b4);
    jsx<0x4E>(w, b2);
    jsx<0xB1>(w, b1);
    il_js8(w); il_js4(w); il_js2(w); il_js1(w);
}

__global__ __launch_bounds__(256, 6) void informed_sampler_kernel(
    const float* __restrict__ tnear,
    const float* __restrict__ tfar,
    const float* __restrict__ dnorm,
    const float* __restrict__ density,
    const float* __restrict__ u,
    float* __restrict__ out)
{
    __shared__ float s_cdf[8 + RPB * CSTR];   // row c at 8 + c*68; row[i] = cdf[i+1]
    __shared__ float s2[RPB * SSTR2];         // half-staging: rank s at c*164 + (s>>4 mod 8)*20 + (s&15)

    const int tid  = threadIdx.x;
    const int lane = tid & 63;
    const int lp   = lane & 15;
    const int c    = tid >> 4;        // ray within block (0..15)
    const int r0   = blockIdx.x * RPB;
    const int r    = r0 + c;

    const float tn  = tnear[r];
    const float tff = tfar[r];
    const float dn  = dnorm[r];
    const float td  = tff - tn;
    const float inv63 = 1.0f / 63.0f;

    // ---- load u: lane lp holds elements e = lp*16 + j ----
    const float4* ub = reinterpret_cast<const float4*>(u + (size_t)r * NSAMP);
    uint32_t w[16];
    {
        float4 a0 = ub[lp * 4 + 0], a1 = ub[lp * 4 + 1], a2 = ub[lp * 4 + 2], a3 = ub[lp * 4 + 3];
        w[ 0]=__float_as_uint(a0.x); w[ 1]=__float_as_uint(a0.y); w[ 2]=__float_as_uint(a0.z); w[ 3]=__float_as_uint(a0.w);
        w[ 4]=__float_as_uint(a1.x); w[ 5]=__float_as_uint(a1.y); w[ 6]=__float_as_uint(a1.z); w[ 7]=__float_as_uint(a1.w);
        w[ 8]=__float_as_uint(a2.x); w[ 9]=__float_as_uint(a2.y); w[10]=__float_as_uint(a2.z); w[11]=__float_as_uint(a2.w);
        w[12]=__float_as_uint(a3.x); w[13]=__float_as_uint(a3.y); w[14]=__float_as_uint(a3.z); w[15]=__float_as_uint(a3.w);
    }

    // ---- CDF build: lane lp owns bins b0..b0+3 ----
    const int b0 = lp * 4;
    float de0 = density[(size_t)(b0 + 0) * NRAYS + r];
    float de1 = density[(size_t)(b0 + 1) * NRAYS + r];
    float de2 = density[(size_t)(b0 + 2) * NRAYS + r];
    float de3 = density[(size_t)(b0 + 3) * NRAYS + r];

    float dl  = td * inv63;
    float dl3 = (lp == 15) ? (TFINALF - (tn + td)) : dl;
    float sd0 = de0 * dl * dn, sd1 = de1 * dl * dn, sd2 = de2 * dl * dn, sd3 = de3 * dl3 * dn;

    float p0 = sd0, p1 = p0 + sd1, p2 = p1 + sd2, p3 = p2 + sd3;
    float tsc   = row16_iscan(p3);
    float carry = dppf<0x111>(tsc);              // exclusive lane-carry (lane0 -> 0, no cancellation)
    float x0 = carry, x1 = carry + p0, x2 = carry + p1, x3 = carry + p2, x4 = carry + p3;
    float e0 = __expf(-x0), e1 = __expf(-x1), e2 = __expf(-x2), e3 = __expf(-x3), e4 = __expf(-x4);
    float wv0 = e0 - e1 + EPSF, wv1 = e1 - e2 + EPSF, wv2 = e2 - e3 + EPSF, wv3 = e3 - e4 + EPSF;
    float q0 = wv0, q1 = q0 + wv1, q2 = q1 + wv2, q3 = q2 + wv3;
    float tww = row16_iscan(q3);
    float cw  = dppf<0x111>(tww);
    float tot = __int_as_float(__builtin_amdgcn_ds_swizzle(__float_as_int(tww), 0x1F0)); // bcast lane15 of 16-group
    float inv = __builtin_amdgcn_rcpf(tot);

    float* cdfrow = &s_cdf[8 + c * CSTR];
    *reinterpret_cast<float4*>(cdfrow + b0) =
        make_float4((cw + q0) * inv, (cw + q1) * inv, (cw + q2) * inv, (cw + q3) * inv);
    __asm__ volatile("s_waitcnt lgkmcnt(0)" ::: "memory");   // wave-local: own group's writes visible
    __builtin_amdgcn_sched_barrier(0);

    // ---- sort u (bits) ascending across the 16-lane group ----
    sort256(w, lane);

    // ---- inverse-CDF: binary search once, then monotone walk ----
    int b = 0;
    {
        float uq0 = __uint_as_float(w[0]);
#pragma unroll
        for (int s = 32; s >= 1; s >>= 1)
            if (cdfrow[b + s - 1] <= uq0) b += s;
    }
    float cb = (b == 0) ? 0.0f : cdfrow[b - 1];  // b=0 reads front pad (selected away)
    float ca = cdfrow[b];
#pragma unroll
    for (int j = 0; j < 16; ++j) {
        float uq = __uint_as_float(w[j]);
        while (ca <= uq && b < 63) { ++b; cb = ca; ca = cdfrow[b]; }
        float dnm = ca - cb;
        dnm = (dnm < EPSF) ? 1.0f : dnm;
        float fb = (float)b;
        float eb = (b == 0)  ? tn  : tn + td * ((fb - 0.5f) * inv63);
        float ea = (b == 63) ? tff : tn + td * ((fb + 0.5f) * inv63);
        float smp = eb + (uq - cb) * __builtin_amdgcn_rcpf(dnm) * (ea - eb);
        smp = fminf(fmaxf(smp, tn), tff);        // exact bounds; NaN-absorbing
        w[j] = __float_as_uint(smp);
    }

    // ---- two-phase transposed output (half-size staging) ----
    float* s2row = &s2[c * SSTR2];
    const int g16 = tid >> 4;       // == c
    const int cc  = tid & 15;

    if (lp < 8) {                    // ranks 0..127
#pragma unroll
        for (int q = 0; q < 4; ++q)
            *reinterpret_cast<uint4*>(&s2row[lp * SKEW + q * 4]) =
                make_uint4(w[4 * q], w[4 * q + 1], w[4 * q + 2], w[4 * q + 3]);
    }
    __syncthreads();
#pragma unroll
    for (int it = 0; it < 8; ++it) {
        int s = it * 16 + g16;
        out[(size_t)s * NRAYS + r0 + cc] = s2[cc * SSTR2 + it * SKEW + g16];
    }
    __syncthreads();
    if (lp >= 8) {                   // ranks 128..255
#pragma unroll
        for (int q = 0; q < 4; ++q)
            *reinterpret_cast<uint4*>(&s2row[(lp - 8) * SKEW + q * 4]) =
                make_uint4(w[4 * q], w[4 * q + 1], w[4 * q + 2], w[4 * q + 3]);
    }
    __syncthreads();
#pragma unroll
    for (int it = 0; it < 8; ++it) {
        int s = 128 + it * 16 + g16;
        out[(size_t)s * NRAYS + r0 + cc] = s2[cc * SSTR2 + it * SKEW + g16];
    }
}

extern "C" void kernel_launch(void* const* d_in, const int* in_sizes, int n_in,
                              void* d_out, int out_size, void* d_ws, size_t ws_size,
                              hipStream_t stream) {
    const float* tnear   = (const float*)d_in[0];
    const float* tfar    = (const float*)d_in[1];
    const float* dnorm   = (const float*)d_in[2];
    const float* density = (const float*)d_in[3];
    const float* u       = (const float*)d_in[4];
    float* out = (float*)d_out;

    dim3 grid(NRAYS / RPB);
    dim3 block(256);
    hipLaunchKernelGGL(informed_sampler_kernel, grid, block, 0, stream,
                       tnear, tfar, dnorm, density, u, out);
}

// Round 8
// 200.553 us; speedup vs baseline: 2.3330x; 1.5339x over previous
//
#include <hip/hip_runtime.h>
#include <stdint.h>

#define NRAYS   262144
#define NSAMP   256
#define RPB     16
#define TFINALF 1e10f
#define EPSF    1e-5f
#define CSTR    68     // cdf row stride (floats)
#define SSTR2   164    // half-staging row stride (floats)
#define SKEW    20     // sub-row skew (floats), 16B aligned

template<int CTRL>
__device__ __forceinline__ uint32_t dppi(uint32_t x) {
    return (uint32_t)__builtin_amdgcn_update_dpp(0, (int)x, CTRL, 0xF, 0xF, false);
}
template<int CTRL>
__device__ __forceinline__ float dppf(float x) {
    return __int_as_float(__builtin_amdgcn_update_dpp(0, __float_as_int(x), CTRL, 0xF, 0xF, false));
}

// inclusive +scan across each 16-lane row
__device__ __forceinline__ float row16_iscan(float x) {
    x += dppf<0x111>(x);
    x += dppf<0x112>(x);
    x += dppf<0x114>(x);
    x += dppf<0x118>(x);
    return x;
}

__device__ __forceinline__ void celo(uint32_t& a, uint32_t& b) {
    uint32_t mn = min(a, b), mx = max(a, b);
    a = mn; b = mx;
}

// cross-lane FLIP pass: partner = mirror-lane (CTRL), element 15-j; up lanes keep max
template<int CTRL>
__device__ __forceinline__ void flipx(uint32_t w[16], bool up) {
#pragma unroll
    for (int p = 0; p < 8; ++p) {
        uint32_t a = w[p], b = w[15 - p];
        uint32_t oa = dppi<CTRL>(b);   // partner lane's w[15-p]
        uint32_t ob = dppi<CTRL>(a);   // partner lane's w[p]
        w[p]      = up ? max(a, oa) : min(a, oa);
        w[15 - p] = up ? max(b, ob) : min(b, ob);
    }
}

// cross-lane XOR pass, same element index; up lanes keep max
template<int CTRL>
__device__ __forceinline__ void jsx(uint32_t w[16], bool up) {
#pragma unroll
    for (int j = 0; j < 16; ++j) {
        uint32_t o = dppi<CTRL>(w[j]);
        w[j] = up ? max(w[j], o) : min(w[j], o);
    }
}
// lane^4 via ds_swizzle (offload to DS pipe)
__device__ __forceinline__ void jsx_swz4(uint32_t w[16], bool up) {
#pragma unroll
    for (int j = 0; j < 16; ++j) {
        uint32_t o = (uint32_t)__builtin_amdgcn_ds_swizzle((int)w[j], 0x101F);
        w[j] = up ? max(w[j], o) : min(w[j], o);
    }
}

// in-lane min-low passes (static)
__device__ __forceinline__ void il_js8(uint32_t w[16]) {
#pragma unroll
    for (int j = 0; j < 8; ++j) celo(w[j], w[j + 8]);
}
__device__ __forceinline__ void il_js4(uint32_t w[16]) {
#pragma unroll
    for (int h = 0; h < 16; h += 8)
#pragma unroll
        for (int j = 0; j < 4; ++j) celo(w[h + j], w[h + j + 4]);
}
__device__ __forceinline__ void il_js2(uint32_t w[16]) {
#pragma unroll
    for (int h = 0; h < 16; h += 4) { celo(w[h], w[h + 2]); celo(w[h + 1], w[h + 3]); }
}
__device__ __forceinline__ void il_js1(uint32_t w[16]) {
#pragma unroll
    for (int j = 0; j < 16; j += 2) celo(w[j], w[j + 1]);
}

// normalized bitonic sort of 256 (16 lanes x 16 elems, e = lp*16 + j), ascending
__device__ __forceinline__ void sort256(uint32_t w[16], int lane) {
    // m=2
    il_js1(w);
    // m=4: flip + js1
#pragma unroll
    for (int h = 0; h < 16; h += 4) { celo(w[h], w[h + 3]); celo(w[h + 1], w[h + 2]); }
    il_js1(w);
    // m=8
#pragma unroll
    for (int h = 0; h < 16; h += 8) {
        celo(w[h], w[h + 7]); celo(w[h + 1], w[h + 6]);
        celo(w[h + 2], w[h + 5]); celo(w[h + 3], w[h + 4]);
    }
    il_js2(w); il_js1(w);
    // m=16
#pragma unroll
    for (int j = 0; j < 8; ++j) celo(w[j], w[15 - j]);
    il_js4(w); il_js2(w); il_js1(w);

    const bool b1 = (lane & 1) != 0, b2 = (lane & 2) != 0;
    const bool b4 = (lane & 4) != 0, b8 = (lane & 8) != 0;
    // m=32: flip across lane^1 (mirror within 2 lanes)
    flipx<0xB1>(w, b1);
    il_js8(w); il_js4(w); il_js2(w); il_js1(w);
    // m=64: flip mirror within 4 lanes (quad_perm [3,2,1,0])
    flipx<0x1B>(w, b2);
    jsx<0xB1>(w, b1);
    il_js8(w); il_js4(w); il_js2(w); il_js1(w);
    // m=128: flip row_half_mirror
    flipx<0x141>(w, b4);
    jsx<0x4E>(w, b2);
    jsx<0xB1>(w, b1);
    il_js8(w); il_js4(w); il_js2(w); il_js1(w);
    // m=256: flip row_mirror
    flipx<0x140>(w, b8);
    jsx_swz4(w, b4);
    jsx<0x4E>(w, b2);
    jsx<0xB1>(w, b1);
    il_js8(w); il_js4(w); il_js2(w); il_js1(w);
}

__global__ __launch_bounds__(256) void informed_sampler_kernel(
    const float* __restrict__ tnear,
    const float* __restrict__ tfar,
    const float* __restrict__ dnorm,
    const float* __restrict__ density,
    const float* __restrict__ u,
    float* __restrict__ out)
{
    __shared__ float s_cdf[8 + RPB * CSTR];   // row c at 8 + c*68; row[i] = cdf[i+1]
    __shared__ float s2[RPB * SSTR2];         // half-staging: rank s of ray c at c*164 + ((s>>4) mod 8)*20 + (s&15)

    const int tid  = threadIdx.x;
    const int lane = tid & 63;
    const int lp   = lane & 15;
    const int c    = tid >> 4;        // ray within block (0..15)
    const int r0   = blockIdx.x * RPB;
    const int r    = r0 + c;

    const float tn  = tnear[r];
    const float tff = tfar[r];
    const float dn  = dnorm[r];
    const float td  = tff - tn;
    const float inv63 = 1.0f / 63.0f;

    // ---- load u: lane lp holds elements e = lp*16 + j ----
    const float4* ub = reinterpret_cast<const float4*>(u + (size_t)r * NSAMP);
    uint32_t w[16];
    {
        float4 a0 = ub[lp * 4 + 0], a1 = ub[lp * 4 + 1], a2 = ub[lp * 4 + 2], a3 = ub[lp * 4 + 3];
        w[ 0]=__float_as_uint(a0.x); w[ 1]=__float_as_uint(a0.y); w[ 2]=__float_as_uint(a0.z); w[ 3]=__float_as_uint(a0.w);
        w[ 4]=__float_as_uint(a1.x); w[ 5]=__float_as_uint(a1.y); w[ 6]=__float_as_uint(a1.z); w[ 7]=__float_as_uint(a1.w);
        w[ 8]=__float_as_uint(a2.x); w[ 9]=__float_as_uint(a2.y); w[10]=__float_as_uint(a2.z); w[11]=__float_as_uint(a2.w);
        w[12]=__float_as_uint(a3.x); w[13]=__float_as_uint(a3.y); w[14]=__float_as_uint(a3.z); w[15]=__float_as_uint(a3.w);
    }

    // ---- CDF build: lane lp owns bins b0..b0+3 ----
    const int b0 = lp * 4;
    float de0 = density[(size_t)(b0 + 0) * NRAYS + r];
    float de1 = density[(size_t)(b0 + 1) * NRAYS + r];
    float de2 = density[(size_t)(b0 + 2) * NRAYS + r];
    float de3 = density[(size_t)(b0 + 3) * NRAYS + r];

    float dl  = td * inv63;
    float dl3 = (lp == 15) ? (TFINALF - (tn + td)) : dl;
    float sd0 = de0 * dl * dn, sd1 = de1 * dl * dn, sd2 = de2 * dl * dn, sd3 = de3 * dl3 * dn;

    float p0 = sd0, p1 = p0 + sd1, p2 = p1 + sd2, p3 = p2 + sd3;
    float tsc   = row16_iscan(p3);
    float carry = dppf<0x111>(tsc);              // exclusive lane-carry (lane0 -> 0, no cancellation)
    float x0 = carry, x1 = carry + p0, x2 = carry + p1, x3 = carry + p2, x4 = carry + p3;
    float e0 = __expf(-x0), e1 = __expf(-x1), e2 = __expf(-x2), e3 = __expf(-x3), e4 = __expf(-x4);
    float wv0 = e0 - e1 + EPSF, wv1 = e1 - e2 + EPSF, wv2 = e2 - e3 + EPSF, wv3 = e3 - e4 + EPSF;
    float q0 = wv0, q1 = q0 + wv1, q2 = q1 + wv2, q3 = q2 + wv3;
    float tww = row16_iscan(q3);
    float cw  = dppf<0x111>(tww);
    float tot = __int_as_float(__builtin_amdgcn_ds_swizzle(__float_as_int(tww), 0x1F0)); // bcast lane15 of 16-group
    float inv = __builtin_amdgcn_rcpf(tot);

    float* cdfrow = &s_cdf[8 + c * CSTR];
    *reinterpret_cast<float4*>(cdfrow + b0) =
        make_float4((cw + q0) * inv, (cw + q1) * inv, (cw + q2) * inv, (cw + q3) * inv);
    __asm__ volatile("s_waitcnt lgkmcnt(0)" ::: "memory");   // wave-local: own group's writes visible
    __builtin_amdgcn_sched_barrier(0);

    // ---- sort u (bits) ascending across the 16-lane group ----
    sort256(w, lane);

    // ---- inverse-CDF: branchless binary search per element (sorted u ->
    //      clustered, mostly-broadcast LDS probes; no data-dependent CFG) ----
#pragma unroll
    for (int j = 0; j < 16; ++j) {
        float uq = __uint_as_float(w[j]);
        int b = 0;                       // b = #{i in 0..63 : row[i] <= uq}, row[i]=cdf[i+1]
#pragma unroll
        for (int s = 32; s >= 1; s >>= 1)
            if (cdfrow[b + s - 1] <= uq) b += s;
        float cbm = cdfrow[b - 1];       // b=0 reads front pad (selected away)
        float ca  = cdfrow[b];
        float cb  = (b == 0) ? 0.0f : cbm;
        float dnm = ca - cb;
        dnm = (dnm < EPSF) ? 1.0f : dnm;
        float fb = (float)b;
        float eb = (b == 0)  ? tn  : tn + td * ((fb - 0.5f) * inv63);
        float ea = (b == 63) ? tff : tn + td * ((fb + 0.5f) * inv63);
        float smp = eb + (uq - cb) * __builtin_amdgcn_rcpf(dnm) * (ea - eb);
        smp = fminf(fmaxf(smp, tn), tff);        // exact bounds; NaN-absorbing
        w[j] = __float_as_uint(smp);
    }

    // ---- two-phase transposed output (half-size staging) ----
    float* s2row = &s2[c * SSTR2];
    const int g16 = tid >> 4;       // == c
    const int cc  = tid & 15;

    if (lp < 8) {                    // ranks 0..127
#pragma unroll
        for (int q = 0; q < 4; ++q)
            *reinterpret_cast<uint4*>(&s2row[lp * SKEW + q * 4]) =
                make_uint4(w[4 * q], w[4 * q + 1], w[4 * q + 2], w[4 * q + 3]);
    }
    __syncthreads();
#pragma unroll
    for (int it = 0; it < 8; ++it) {
        int s = it * 16 + g16;
        out[(size_t)s * NRAYS + r0 + cc] = s2[cc * SSTR2 + it * SKEW + g16];
    }
    __syncthreads();
    if (lp >= 8) {                   // ranks 128..255
#pragma unroll
        for (int q = 0; q < 4; ++q)
            *reinterpret_cast<uint4*>(&s2row[(lp - 8) * SKEW + q * 4]) =
                make_uint4(w[4 * q], w[4 * q + 1], w[4 * q + 2], w[4 * q + 3]);
    }
    __syncthreads();
#pragma unroll
    for (int it = 0; it < 8; ++it) {
        int s = 128 + it * 16 + g16;
        out[(size_t)s * NRAYS + r0 + cc] = s2[cc * SSTR2 + it * SKEW + g16];
    }
}

extern "C" void kernel_launch(void* const* d_in, const int* in_sizes, int n_in,
                              void* d_out, int out_size, void* d_ws, size_t ws_size,
                              hipStream_t stream) {
    const float* tnear   = (const float*)d_in[0];
    const float* tfar    = (const float*)d_in[1];
    const float* dnorm   = (const float*)d_in[2];
    const float* density = (const float*)d_in[3];
    const float* u       = (const float*)d_in[4];
    float* out = (float*)d_out;

    dim3 grid(NRAYS / RPB);
    dim3 block(256);
    hipLaunchKernelGGL(informed_sampler_kernel, grid, block, 0, stream,
                       tnear, tfar, dnorm, density, u, out);
}

// Round 10
// 197.760 us; speedup vs baseline: 2.3660x; 1.0141x over previous
//
#include <hip/hip_runtime.h>
#include <stdint.h>

#define NRAYS   262144
#define NSAMP   256
#define RPB     16
#define TFINALF 1e10f
#define EPSF    1e-5f
#define CSTR    72     // cdf row stride: 72 ≡ 8 (mod 32) -> 4 rays/wave on disjoint bank octets
#define SSTR2   164    // half-staging row stride (floats)
#define SKEW    20     // sub-row skew (floats), 16B aligned

template<int CTRL>
__device__ __forceinline__ uint32_t dppi(uint32_t x) {
    return (uint32_t)__builtin_amdgcn_update_dpp(0, (int)x, CTRL, 0xF, 0xF, false);
}
template<int CTRL>
__device__ __forceinline__ float dppf(float x) {
    return __int_as_float(__builtin_amdgcn_update_dpp(0, __float_as_int(x), CTRL, 0xF, 0xF, false));
}
template<int PAT>
__device__ __forceinline__ float swzf(float x) {
    return __int_as_float(__builtin_amdgcn_ds_swizzle(__float_as_int(x), PAT));
}

// inclusive +scan across each 16-lane row
__device__ __forceinline__ float row16_iscan(float x) {
    x += dppf<0x111>(x);
    x += dppf<0x112>(x);
    x += dppf<0x114>(x);
    x += dppf<0x118>(x);
    return x;
}

__device__ __forceinline__ void celo(uint32_t& a, uint32_t& b) {
    uint32_t mn = min(a, b), mx = max(a, b);
    a = mn; b = mx;
}

// cross-lane FLIP pass: partner = mirror-lane (CTRL), element 15-j; up lanes keep max
template<int CTRL>
__device__ __forceinline__ void flipx(uint32_t w[16], bool up) {
#pragma unroll
    for (int p = 0; p < 8; ++p) {
        uint32_t a = w[p], b = w[15 - p];
        uint32_t oa = dppi<CTRL>(b);   // partner lane's w[15-p]
        uint32_t ob = dppi<CTRL>(a);   // partner lane's w[p]
        w[p]      = up ? max(a, oa) : min(a, oa);
        w[15 - p] = up ? max(b, ob) : min(b, ob);
    }
}

// cross-lane XOR pass, same element index; up lanes keep max
template<int CTRL>
__device__ __forceinline__ void jsx(uint32_t w[16], bool up) {
#pragma unroll
    for (int j = 0; j < 16; ++j) {
        uint32_t o = dppi<CTRL>(w[j]);
        w[j] = up ? max(w[j], o) : min(w[j], o);
    }
}
// lane^4 via ds_swizzle (offload to DS pipe)
__device__ __forceinline__ void jsx_swz4(uint32_t w[16], bool up) {
#pragma unroll
    for (int j = 0; j < 16; ++j) {
        uint32_t o = (uint32_t)__builtin_amdgcn_ds_swizzle((int)w[j], 0x101F);
        w[j] = up ? max(w[j], o) : min(w[j], o);
    }
}

// in-lane min-low passes (static)
__device__ __forceinline__ void il_js8(uint32_t w[16]) {
#pragma unroll
    for (int j = 0; j < 8; ++j) celo(w[j], w[j + 8]);
}
__device__ __forceinline__ void il_js4(uint32_t w[16]) {
#pragma unroll
    for (int h = 0; h < 16; h += 8)
#pragma unroll
        for (int j = 0; j < 4; ++j) celo(w[h + j], w[h + j + 4]);
}
__device__ __forceinline__ void il_js2(uint32_t w[16]) {
#pragma unroll
    for (int h = 0; h < 16; h += 4) { celo(w[h], w[h + 2]); celo(w[h + 1], w[h + 3]); }
}
__device__ __forceinline__ void il_js1(uint32_t w[16]) {
#pragma unroll
    for (int j = 0; j < 16; j += 2) celo(w[j], w[j + 1]);
}

// normalized bitonic sort of 256 (16 lanes x 16 elems, e = lp*16 + j), ascending
__device__ __forceinline__ void sort256(uint32_t w[16], int lane) {
    // m=2
    il_js1(w);
    // m=4: flip + js1
#pragma unroll
    for (int h = 0; h < 16; h += 4) { celo(w[h], w[h + 3]); celo(w[h + 1], w[h + 2]); }
    il_js1(w);
    // m=8
#pragma unroll
    for (int h = 0; h < 16; h += 8) {
        celo(w[h], w[h + 7]); celo(w[h + 1], w[h + 6]);
        celo(w[h + 2], w[h + 5]); celo(w[h + 3], w[h + 4]);
    }
    il_js2(w); il_js1(w);
    // m=16
#pragma unroll
    for (int j = 0; j < 8; ++j) celo(w[j], w[15 - j]);
    il_js4(w); il_js2(w); il_js1(w);

    const bool b1 = (lane & 1) != 0, b2 = (lane & 2) != 0;
    const bool b4 = (lane & 4) != 0, b8 = (lane & 8) != 0;
    // m=32: flip across lane^1 (mirror within 2 lanes)
    flipx<0xB1>(w, b1);
    il_js8(w); il_js4(w); il_js2(w); il_js1(w);
    // m=64: flip mirror within 4 lanes (quad_perm [3,2,1,0])
    flipx<0x1B>(w, b2);
    jsx<0xB1>(w, b1);
    il_js8(w); il_js4(w); il_js2(w); il_js1(w);
    // m=128: flip row_half_mirror
    flipx<0x141>(w, b4);
    jsx<0x4E>(w, b2);
    jsx<0xB1>(w, b1);
    il_js8(w); il_js4(w); il_js2(w); il_js1(w);
    // m=256: flip row_mirror
    flipx<0x140>(w, b8);
    jsx_swz4(w, b4);
    jsx<0x4E>(w, b2);
    jsx<0xB1>(w, b1);
    il_js8(w); il_js4(w); il_js2(w); il_js1(w);
}

__global__ __launch_bounds__(256) void informed_sampler_kernel(
    const float* __restrict__ tnear,
    const float* __restrict__ tfar,
    const float* __restrict__ dnorm,
    const float* __restrict__ density,
    const float* __restrict__ u,
    float* __restrict__ out)
{
    __shared__ float s_cdf[8 + RPB * CSTR];   // row c at 8 + c*72; row[i] = cdf[i+1]
    __shared__ float s2[RPB * SSTR2];         // half-staging

    const int tid  = threadIdx.x;
    const int lane = tid & 63;
    const int lp   = lane & 15;
    const int c    = tid >> 4;        // ray within block (0..15)
    const int r0   = blockIdx.x * RPB;
    const int r    = r0 + c;

    const float tn  = tnear[r];
    const float tff = tfar[r];
    const float dn  = dnorm[r];
    const float td  = tff - tn;
    const float inv63 = 1.0f / 63.0f;
    const float tdi = td * inv63;     // one coarse-bin width

    // ---- load u: lane lp holds elements e = lp*16 + j ----
    const float4* ub = reinterpret_cast<const float4*>(u + (size_t)r * NSAMP);
    uint32_t w[16];
    {
        float4 a0 = ub[lp * 4 + 0], a1 = ub[lp * 4 + 1], a2 = ub[lp * 4 + 2], a3 = ub[lp * 4 + 3];
        w[ 0]=__float_as_uint(a0.x); w[ 1]=__float_as_uint(a0.y); w[ 2]=__float_as_uint(a0.z); w[ 3]=__float_as_uint(a0.w);
        w[ 4]=__float_as_uint(a1.x); w[ 5]=__float_as_uint(a1.y); w[ 6]=__float_as_uint(a1.z); w[ 7]=__float_as_uint(a1.w);
        w[ 8]=__float_as_uint(a2.x); w[ 9]=__float_as_uint(a2.y); w[10]=__float_as_uint(a2.z); w[11]=__float_as_uint(a2.w);
        w[12]=__float_as_uint(a3.x); w[13]=__float_as_uint(a3.y); w[14]=__float_as_uint(a3.z); w[15]=__float_as_uint(a3.w);
    }

    // ---- CDF build: lane lp owns bins b0..b0+3 ----
    const int b0 = lp * 4;
    float de0 = density[(size_t)(b0 + 0) * NRAYS + r];
    float de1 = density[(size_t)(b0 + 1) * NRAYS + r];
    float de2 = density[(size_t)(b0 + 2) * NRAYS + r];
    float de3 = density[(size_t)(b0 + 3) * NRAYS + r];

    float dl3 = (lp == 15) ? (TFINALF - (tn + td)) : tdi;
    float sd0 = de0 * tdi * dn, sd1 = de1 * tdi * dn, sd2 = de2 * tdi * dn, sd3 = de3 * dl3 * dn;

    float p0 = sd0, p1 = p0 + sd1, p2 = p1 + sd2, p3 = p2 + sd3;
    float tsc   = row16_iscan(p3);
    float carry = dppf<0x111>(tsc);              // exclusive lane-carry (lane0 -> 0, no cancellation)
    float x0 = carry, x1 = carry + p0, x2 = carry + p1, x3 = carry + p2, x4 = carry + p3;
    float e0 = __expf(-x0), e1 = __expf(-x1), e2 = __expf(-x2), e3 = __expf(-x3), e4 = __expf(-x4);
    float wv0 = e0 - e1 + EPSF, wv1 = e1 - e2 + EPSF, wv2 = e2 - e3 + EPSF, wv3 = e3 - e4 + EPSF;
    float q0 = wv0, q1 = q0 + wv1, q2 = q1 + wv2, q3 = q2 + wv3;
    float tww = row16_iscan(q3);
    float cw  = dppf<0x111>(tww);
    float tot = swzf<0x1F0>(tww);                // bcast lane15 of 16-group
    float inv = __builtin_amdgcn_rcpf(tot);

    float rv0 = (cw + q0) * inv, rv1 = (cw + q1) * inv,
          rv2 = (cw + q2) * inv, rv3 = (cw + q3) * inv;   // row[b0..b0+3]
    float* cdfrow = &s_cdf[8 + c * CSTR];
    *reinterpret_cast<float4*>(cdfrow + b0) = make_float4(rv0, rv1, rv2, rv3);

    // register copies of the probe tree's upper levels (rv3 of lanes 1,3,5,7,9,11,13)
    float r7  = swzf<0x030>(rv3);   // row[7]  (lp=1)
    float r15 = swzf<0x070>(rv3);   // row[15] (lp=3)
    float r23 = swzf<0x0B0>(rv3);   // row[23] (lp=5)
    float r31 = swzf<0x0F0>(rv3);   // row[31] (lp=7)
    float r39 = swzf<0x130>(rv3);   // row[39] (lp=9)
    float r47 = swzf<0x170>(rv3);   // row[47] (lp=11)
    float r55 = swzf<0x1B0>(rv3);   // row[55] (lp=13)

    // ---- sort u (bits) ascending across the 16-lane group (pure VALU/DPP;
    //      overlaps the cdf store latency) ----
    sort256(w, lane);

    __asm__ volatile("s_waitcnt lgkmcnt(0)" ::: "memory");  // cdf visible (belt & braces)

    // ---- inverse-CDF: 3 register levels + 3 clustered LDS probes + read2 pair ----
#pragma unroll
    for (int j = 0; j < 16; ++j) {
        float uq = __uint_as_float(w[j]);
        bool  c32 = (r31 <= uq);
        int   b   = c32 ? 32 : 0;
        float p16 = c32 ? r47 : r15;
        bool  t16 = (p16 <= uq);
        b += t16 ? 16 : 0;
        float pA = c32 ? r39 : r7;
        float pB = c32 ? r55 : r23;
        float p8 = t16 ? pB : pA;
        b += (p8 <= uq) ? 8 : 0;
        if (cdfrow[b + 3] <= uq) b += 4;
        if (cdfrow[b + 1] <= uq) b += 2;
        if (cdfrow[b]     <= uq) b += 1;
        float cbm = cdfrow[b - 1];       // adjacent pair -> ds_read2_b32
        float ca  = cdfrow[b];
        float cb  = (b == 0) ? 0.0f : cbm;
        float dnm = ca - cb;
        dnm = (dnm < EPSF) ? 1.0f : dnm;
        float fb = (float)b;
        float eb = fmaf(fmaxf(fb - 0.5f, 0.0f), tdi, tn);   // exact at b=0
        float ea = fmaf(fminf(fb + 0.5f, 63.0f), tdi, tn);  // exact at b=63
        float smp = eb + (uq - cb) * __builtin_amdgcn_rcpf(dnm) * (ea - eb);
        smp = fminf(fmaxf(smp, tn), tff);        // exact bounds; NaN-absorbing
        w[j] = __float_as_uint(smp);
    }

    // ---- two-phase transposed output (half-size staging) ----
    float* s2row = &s2[c * SSTR2];
    const int g16 = tid >> 4;       // == c
    const int cc  = tid & 15;

    if (lp < 8) {                    // ranks 0..127
#pragma unroll
        for (int q = 0; q < 4; ++q)
            *reinterpret_cast<uint4*>(&s2row[lp * SKEW + q * 4]) =
                make_uint4(w[4 * q], w[4 * q + 1], w[4 * q + 2], w[4 * q + 3]);
    }
    __syncthreads();
#pragma unroll
    for (int it = 0; it < 8; ++it) {
        int s = it * 16 + g16;
        out[(size_t)s * NRAYS + r0 + cc] = s2[cc * SSTR2 + it * SKEW + g16];
    }
    __syncthreads();
    if (lp >= 8) {                   // ranks 128..255
#pragma unroll
        for (int q = 0; q < 4; ++q)
            *reinterpret_cast<uint4*>(&s2row[(lp - 8) * SKEW + q * 4]) =
                make_uint4(w[4 * q], w[4 * q + 1], w[4 * q + 2], w[4 * q + 3]);
    }
    __syncthreads();
#pragma unroll
    for (int it = 0; it < 8; ++it) {
        int s = 128 + it * 16 + g16;
        out[(size_t)s * NRAYS + r0 + cc] = s2[cc * SSTR2 + it * SKEW + g16];
    }
}

extern "C" void kernel_launch(void* const* d_in, const int* in_sizes, int n_in,
                              void* d_out, int out_size, void* d_ws, size_t ws_size,
                              hipStream_t stream) {
    const float* tnear   = (const float*)d_in[0];
    const float* tfar    = (const float*)d_in[1];
    const float* dnorm   = (const float*)d_in[2];
    const float* density = (const float*)d_in[3];
    const float* u       = (const float*)d_in[4];
    float* out = (float*)d_out;

    dim3 grid(NRAYS / RPB);
    dim3 block(256);
    hipLaunchKernelGGL(informed_sampler_kernel, grid, block, 0, stream,
                       tnear, tfar, dnorm, density, u, out);
}